// Round 1
// baseline (419.939 us; speedup 1.0000x reference)
//
#include <hip/hip_runtime.h>

// ---------------- CSR construction ----------------

__global__ void k_hist(const int* __restrict__ dst, int* __restrict__ deg, int E) {
    int i = blockIdx.x * blockDim.x + threadIdx.x;
    if (i < E) atomicAdd(&deg[dst[i]], 1);
}

__global__ void k_seg_bounds(const int* __restrict__ batch, int* __restrict__ ss,
                             int* __restrict__ se, int N) {
    int i = blockIdx.x * blockDim.x + threadIdx.x;
    if (i < N) {
        int b = batch[i];
        atomicMin(&ss[b], i);
        atomicMax(&se[b], i + 1);
    }
}

__global__ void k_scan_part(const int* __restrict__ deg, int* __restrict__ offs,
                            int* __restrict__ bsum, int N) {
    __shared__ int sd[256];
    int t = threadIdx.x;
    int i = blockIdx.x * 256 + t;
    int v = (i < N) ? deg[i] : 0;
    sd[t] = v;
    __syncthreads();
    int sum = v;
    for (int d = 1; d < 256; d <<= 1) {
        int add = (t >= d) ? sd[t - d] : 0;
        __syncthreads();
        sum += add;
        sd[t] = sum;
        __syncthreads();
    }
    if (i < N) offs[i] = sum - v;              // exclusive within block
    if (t == 255) bsum[blockIdx.x] = sum;      // block total
}

__global__ void k_scan_blk(int* __restrict__ bsum, int nb) {
    __shared__ int sd[256];
    int t = threadIdx.x;
    int v = (t < nb) ? bsum[t] : 0;
    sd[t] = v;
    __syncthreads();
    int sum = v;
    for (int d = 1; d < 256; d <<= 1) {
        int add = (t >= d) ? sd[t - d] : 0;
        __syncthreads();
        sum += add;
        sd[t] = sum;
        __syncthreads();
    }
    if (t < nb) bsum[t] = sum - v;             // exclusive block prefix
}

__global__ void k_finalize(int* __restrict__ offs, const int* __restrict__ bsum,
                           const int* __restrict__ deg, float* __restrict__ dinv,
                           int* __restrict__ cursor, int N) {
    int i = blockIdx.x * blockDim.x + threadIdx.x;
    if (i < N) {
        int o = offs[i] + bsum[i >> 8];
        offs[i] = o;
        cursor[i] = o;
        dinv[i] = rsqrtf((float)deg[i] + 1.0f);   // deg + 1 self-loop
    }
}

__global__ void k_scatter(const int* __restrict__ src, const int* __restrict__ dst,
                          int* __restrict__ cursor, int* __restrict__ ssrc, int E) {
    int i = blockIdx.x * blockDim.x + threadIdx.x;
    if (i < E) {
        int p = atomicAdd(&cursor[dst[i]], 1);
        ssrc[p] = src[i];
    }
}

// ---------------- per-layer compute ----------------

// out[v][f] = (in[v] @ W)[f] * dinv[v];  in: [N,K], W: [K,64], out: [N,64]
// block = 256 threads = 4 waves; each wave handles 4 nodes; lane = output feature.
__global__ void k_gemm_scale(const float* __restrict__ in, const float* __restrict__ W,
                             const float* __restrict__ dinv, float* __restrict__ out,
                             int N, int K) {
    __shared__ float sW[128 * 64];
    int t = threadIdx.x;
    for (int i = t; i < K * 64; i += 256) sW[i] = W[i];
    __syncthreads();
    int wave = t >> 6, lane = t & 63;
    int node0 = blockIdx.x * 16 + wave * 4;
    if (node0 >= N) return;
    if (node0 + 4 <= N) {
        float acc0 = 0.f, acc1 = 0.f, acc2 = 0.f, acc3 = 0.f;
        const float* r = in + (size_t)node0 * K;
        for (int k = 0; k < K; k += 4) {
            float4 x0 = *(const float4*)(r + k);
            float4 x1 = *(const float4*)(r + K + k);
            float4 x2 = *(const float4*)(r + 2 * K + k);
            float4 x3 = *(const float4*)(r + 3 * K + k);
            float w0 = sW[(k + 0) * 64 + lane];
            float w1 = sW[(k + 1) * 64 + lane];
            float w2 = sW[(k + 2) * 64 + lane];
            float w3 = sW[(k + 3) * 64 + lane];
            acc0 += x0.x * w0 + x0.y * w1 + x0.z * w2 + x0.w * w3;
            acc1 += x1.x * w0 + x1.y * w1 + x1.z * w2 + x1.w * w3;
            acc2 += x2.x * w0 + x2.y * w1 + x2.z * w2 + x2.w * w3;
            acc3 += x3.x * w0 + x3.y * w1 + x3.z * w2 + x3.w * w3;
        }
        out[(size_t)(node0 + 0) * 64 + lane] = acc0 * dinv[node0 + 0];
        out[(size_t)(node0 + 1) * 64 + lane] = acc1 * dinv[node0 + 1];
        out[(size_t)(node0 + 2) * 64 + lane] = acc2 * dinv[node0 + 2];
        out[(size_t)(node0 + 3) * 64 + lane] = acc3 * dinv[node0 + 3];
    } else {
        for (int n = node0; n < N; ++n) {
            const float* r = in + (size_t)n * K;
            float a = 0.f;
            for (int k = 0; k < K; ++k) a += r[k] * sW[k * 64 + lane];
            out[(size_t)n * 64 + lane] = a * dinv[n];
        }
    }
}

// out[v][f] = relu?( dinv[v] * (hs[v][f] + sum_{j in CSR(v)} hs[ssrc[j]][f]) + bias[f] )
// block = 256 threads = 4 waves; one wave per node; lane = feature.
__global__ void k_aggregate(const float* __restrict__ hs, const int* __restrict__ ssrc,
                            const int* __restrict__ offs, const int* __restrict__ deg,
                            const float* __restrict__ dinv, const float* __restrict__ bias,
                            float* __restrict__ out, int N, int do_relu) {
    int t = threadIdx.x;
    int wave = t >> 6, lane = t & 63;
    int v = blockIdx.x * 4 + wave;
    if (v >= N) return;
    int start = offs[v];
    int cnt = deg[v];
    float acc = hs[(size_t)v * 64 + lane];      // self-loop term (pre-scaled by dinv[v])
    int j = 0;
    for (; j + 4 <= cnt; j += 4) {
        int s0 = ssrc[start + j + 0];
        int s1 = ssrc[start + j + 1];
        int s2 = ssrc[start + j + 2];
        int s3 = ssrc[start + j + 3];
        float h0 = hs[(size_t)s0 * 64 + lane];
        float h1 = hs[(size_t)s1 * 64 + lane];
        float h2 = hs[(size_t)s2 * 64 + lane];
        float h3 = hs[(size_t)s3 * 64 + lane];
        acc += h0; acc += h1; acc += h2; acc += h3;
    }
    for (; j < cnt; ++j) {
        int s = ssrc[start + j];
        acc += hs[(size_t)s * 64 + lane];
    }
    float o = acc * dinv[v] + bias[lane];
    if (do_relu) o = fmaxf(o, 0.0f);
    out[(size_t)v * 64 + lane] = o;
}

// one block (64 threads = 1 wave) per graph: mean-pool its node range, then 64x10 head.
__global__ void k_pool_classify(const float* __restrict__ h, const int* __restrict__ ss,
                                const int* __restrict__ se, const float* __restrict__ Wl,
                                const float* __restrict__ bl, float* __restrict__ out,
                                int C) {
    int b = blockIdx.x;
    int lane = threadIdx.x;
    int s = ss[b], e = se[b];
    float acc = 0.0f;
    for (int v = s; v < e; ++v) acc += h[(size_t)v * 64 + lane];
    int cnt = e - s;
    if (cnt < 1) cnt = 1;                        // max(cnt,1); empty graph -> acc stays 0
    float pooled = acc / (float)cnt;
    for (int c = 0; c < C; ++c) {
        float tt = pooled * Wl[lane * C + c];
        for (int off = 32; off > 0; off >>= 1) tt += __shfl_down(tt, off);
        if (lane == 0) out[b * C + c] = tt + bl[c];
    }
}

// ---------------- launch ----------------

extern "C" void kernel_launch(void* const* d_in, const int* in_sizes, int n_in,
                              void* d_out, int out_size, void* d_ws, size_t ws_size,
                              hipStream_t stream) {
    const float* x    = (const float*)d_in[0];
    const int*   ei   = (const int*)d_in[1];
    const int*   batch= (const int*)d_in[2];
    const float* W1   = (const float*)d_in[3];
    const float* b1   = (const float*)d_in[4];
    const float* W2   = (const float*)d_in[5];
    const float* b2   = (const float*)d_in[6];
    const float* W3   = (const float*)d_in[7];
    const float* b3   = (const float*)d_in[8];
    const float* Wl   = (const float*)d_in[9];
    const float* bl   = (const float*)d_in[10];
    float* out = (float*)d_out;

    const int N = in_sizes[2];          // 50000
    const int E = in_sizes[1] / 2;      // 800000
    const int F = in_sizes[0] / N;      // 128
    const int C = 10;
    const int B = out_size / C;         // 512

    char* ws = (char*)d_ws;
    auto alloc = [&](size_t bytes) {
        char* p = ws;
        ws += (bytes + 255) & ~(size_t)255;
        return p;
    };
    float* dinv    = (float*)alloc((size_t)N * 4);
    int*   deg     = (int*)alloc((size_t)N * 4);
    int*   offs    = (int*)alloc((size_t)N * 4);
    int*   cursor  = (int*)alloc((size_t)N * 4);
    int*   bsum    = (int*)alloc(256 * 4);
    int*   segs    = (int*)alloc((size_t)B * 4);
    int*   sege    = (int*)alloc((size_t)B * 4);
    int*   ssrc    = (int*)alloc((size_t)E * 4);
    float* bufA    = (float*)alloc((size_t)N * 64 * 4);
    float* bufB    = (float*)alloc((size_t)N * 64 * 4);

    const int* src = ei;
    const int* dst = ei + E;

    hipMemsetAsync(deg, 0, (size_t)N * 4, stream);
    hipMemsetAsync(segs, 0x7f, (size_t)B * 4, stream);  // ~INT_MAX for atomicMin
    hipMemsetAsync(sege, 0, (size_t)B * 4, stream);

    int nbE = (E + 255) / 256;
    int nbN = (N + 255) / 256;

    k_hist<<<nbE, 256, 0, stream>>>(dst, deg, E);
    k_seg_bounds<<<nbN, 256, 0, stream>>>(batch, segs, sege, N);
    k_scan_part<<<nbN, 256, 0, stream>>>(deg, offs, bsum, N);
    k_scan_blk<<<1, 256, 0, stream>>>(bsum, nbN);
    k_finalize<<<nbN, 256, 0, stream>>>(offs, bsum, deg, dinv, cursor, N);
    k_scatter<<<nbE, 256, 0, stream>>>(src, dst, cursor, ssrc, E);

    int gGemm = (N + 15) / 16;
    int gAgg  = (N + 3) / 4;

    // layer 1: x[N,128] @ W1 -> relu(agg)
    k_gemm_scale<<<gGemm, 256, 0, stream>>>(x, W1, dinv, bufA, N, F);
    k_aggregate<<<gAgg, 256, 0, stream>>>(bufA, ssrc, offs, deg, dinv, b1, bufB, N, 1);
    // layer 2
    k_gemm_scale<<<gGemm, 256, 0, stream>>>(bufB, W2, dinv, bufA, N, 64);
    k_aggregate<<<gAgg, 256, 0, stream>>>(bufA, ssrc, offs, deg, dinv, b2, bufB, N, 1);
    // layer 3 (no relu)
    k_gemm_scale<<<gGemm, 256, 0, stream>>>(bufB, W3, dinv, bufA, N, 64);
    k_aggregate<<<gAgg, 256, 0, stream>>>(bufA, ssrc, offs, deg, dinv, b3, bufB, N, 0);

    // mean-pool per graph + linear head
    k_pool_classify<<<B, 64, 0, stream>>>(bufB, segs, sege, Wl, bl, out, C);
}

// Round 2
// 353.441 us; speedup vs baseline: 1.1881x; 1.1881x over previous
//
#include <hip/hip_runtime.h>

// ---------------- CSR construction ----------------

__global__ void k_hist(const int* __restrict__ dst, int* __restrict__ deg, int E) {
    int i = blockIdx.x * blockDim.x + threadIdx.x;
    if (i < E) atomicAdd(&deg[dst[i]], 1);
}

__global__ void k_seg_bounds(const int* __restrict__ batch, int* __restrict__ ss,
                             int* __restrict__ se, int N) {
    int i = blockIdx.x * blockDim.x + threadIdx.x;
    if (i < N) {
        int b = batch[i];
        atomicMin(&ss[b], i);
        atomicMax(&se[b], i + 1);
    }
}

__global__ void k_scan_part(const int* __restrict__ deg, int* __restrict__ offs,
                            int* __restrict__ bsum, int N) {
    __shared__ int sd[256];
    int t = threadIdx.x;
    int i = blockIdx.x * 256 + t;
    int v = (i < N) ? deg[i] : 0;
    sd[t] = v;
    __syncthreads();
    int sum = v;
    for (int d = 1; d < 256; d <<= 1) {
        int add = (t >= d) ? sd[t - d] : 0;
        __syncthreads();
        sum += add;
        sd[t] = sum;
        __syncthreads();
    }
    if (i < N) offs[i] = sum - v;              // exclusive within block
    if (t == 255) bsum[blockIdx.x] = sum;      // block total
}

__global__ void k_scan_blk(int* __restrict__ bsum, int nb) {
    __shared__ int sd[256];
    int t = threadIdx.x;
    int v = (t < nb) ? bsum[t] : 0;
    sd[t] = v;
    __syncthreads();
    int sum = v;
    for (int d = 1; d < 256; d <<= 1) {
        int add = (t >= d) ? sd[t - d] : 0;
        __syncthreads();
        sum += add;
        sd[t] = sum;
        __syncthreads();
    }
    if (t < nb) bsum[t] = sum - v;             // exclusive block prefix
}

__global__ void k_finalize(int* __restrict__ offs, const int* __restrict__ bsum,
                           const int* __restrict__ deg, float* __restrict__ dinv,
                           int* __restrict__ cursor, int N) {
    int i = blockIdx.x * blockDim.x + threadIdx.x;
    if (i < N) {
        int o = offs[i] + bsum[i >> 8];
        offs[i] = o;
        cursor[i] = o;
        dinv[i] = rsqrtf((float)deg[i] + 1.0f);   // deg + 1 self-loop
    }
}

__global__ void k_scatter(const int* __restrict__ src, const int* __restrict__ dst,
                          int* __restrict__ cursor, int* __restrict__ ssrc, int E) {
    int i = blockIdx.x * blockDim.x + threadIdx.x;
    if (i < E) {
        int p = atomicAdd(&cursor[dst[i]], 1);
        ssrc[p] = src[i];
    }
}

// ---------------- per-layer compute ----------------

// out[v][f] = (in[v] @ W)[f] * dinv[v];  in: [N,K], W: [K,64], out: [N,64]
// Register-tiled: block = 64 nodes x 64 feats, 256 threads, 4x4 acc per thread.
// sX staged TRANSPOSED [K][64] with column-per-lane writes (bank = lane%32,
// conflict-free); inner loop = 2x ds_read_b128 + 16 FMA per k.
template <int K>
__global__ __launch_bounds__(256) void k_gemm_tile(const float* __restrict__ in,
                                                   const float* __restrict__ W,
                                                   const float* __restrict__ dinv,
                                                   float* __restrict__ out, int N) {
    __shared__ float sX[K][64];
    __shared__ float sW[K][64];
    int t = threadIdx.x;
    int w = t >> 6, l = t & 63;
    int node0 = blockIdx.x * 64;

    // stage W linearly (coalesced float4)
    for (int i = t; i < K * 16; i += 256)
        ((float4*)&sW[0][0])[i] = ((const float4*)W)[i];

    // stage X transposed: lane = node column, wave w covers k-range [w*K/4, (w+1)*K/4)
    {
        int node = node0 + l;
        bool ok = node < N;
        const float* rp = in + (size_t)node * K;
        for (int k0 = w * (K / 4); k0 < (w + 1) * (K / 4); k0 += 4) {
            float4 v = ok ? *(const float4*)(rp + k0) : make_float4(0.f, 0.f, 0.f, 0.f);
            sX[k0 + 0][l] = v.x;
            sX[k0 + 1][l] = v.y;
            sX[k0 + 2][l] = v.z;
            sX[k0 + 3][l] = v.w;
        }
    }
    __syncthreads();

    int fg  = l & 15;            // feature group 0..15 (4 feats)
    int ngl = w * 4 + (l >> 4);  // node group 0..15 (4 nodes)

    float4 a0 = {0.f, 0.f, 0.f, 0.f};
    float4 a1 = {0.f, 0.f, 0.f, 0.f};
    float4 a2 = {0.f, 0.f, 0.f, 0.f};
    float4 a3 = {0.f, 0.f, 0.f, 0.f};

#pragma unroll 8
    for (int k = 0; k < K; ++k) {
        float4 xv = *(const float4*)(&sX[k][ngl * 4]);
        float4 wv = *(const float4*)(&sW[k][fg * 4]);
        a0.x += xv.x * wv.x; a0.y += xv.x * wv.y; a0.z += xv.x * wv.z; a0.w += xv.x * wv.w;
        a1.x += xv.y * wv.x; a1.y += xv.y * wv.y; a1.z += xv.y * wv.z; a1.w += xv.y * wv.w;
        a2.x += xv.z * wv.x; a2.y += xv.z * wv.y; a2.z += xv.z * wv.z; a2.w += xv.z * wv.w;
        a3.x += xv.w * wv.x; a3.y += xv.w * wv.y; a3.z += xv.w * wv.z; a3.w += xv.w * wv.w;
    }

    int nbase = node0 + ngl * 4;
    float4 accs[4] = {a0, a1, a2, a3};
#pragma unroll
    for (int i = 0; i < 4; ++i) {
        int n = nbase + i;
        if (n < N) {
            float s = dinv[n];
            float4 o = accs[i];
            o.x *= s; o.y *= s; o.z *= s; o.w *= s;
            *(float4*)(out + (size_t)n * 64 + fg * 4) = o;
        }
    }
}

// out[v][f] = relu?( dinv[v] * (hs[v][f] + sum_{j in CSR(v)} hs[ssrc[j]][f]) + bias[f] )
// block = 256 threads = 4 waves; one wave per node; lane = feature.
__global__ void k_aggregate(const float* __restrict__ hs, const int* __restrict__ ssrc,
                            const int* __restrict__ offs, const int* __restrict__ deg,
                            const float* __restrict__ dinv, const float* __restrict__ bias,
                            float* __restrict__ out, int N, int do_relu) {
    int t = threadIdx.x;
    int wave = t >> 6, lane = t & 63;
    int v = blockIdx.x * 4 + wave;
    if (v >= N) return;
    int start = offs[v];
    int cnt = deg[v];
    float acc = hs[(size_t)v * 64 + lane];      // self-loop term (pre-scaled by dinv[v])
    int j = 0;
    for (; j + 4 <= cnt; j += 4) {
        int s0 = ssrc[start + j + 0];
        int s1 = ssrc[start + j + 1];
        int s2 = ssrc[start + j + 2];
        int s3 = ssrc[start + j + 3];
        float h0 = hs[(size_t)s0 * 64 + lane];
        float h1 = hs[(size_t)s1 * 64 + lane];
        float h2 = hs[(size_t)s2 * 64 + lane];
        float h3 = hs[(size_t)s3 * 64 + lane];
        acc += h0; acc += h1; acc += h2; acc += h3;
    }
    for (; j < cnt; ++j) {
        int s = ssrc[start + j];
        acc += hs[(size_t)s * 64 + lane];
    }
    float o = acc * dinv[v] + bias[lane];
    if (do_relu) o = fmaxf(o, 0.0f);
    out[(size_t)v * 64 + lane] = o;
}

// one block (64 threads = 1 wave) per graph: mean-pool its node range, then 64x10 head.
__global__ void k_pool_classify(const float* __restrict__ h, const int* __restrict__ ss,
                                const int* __restrict__ se, const float* __restrict__ Wl,
                                const float* __restrict__ bl, float* __restrict__ out,
                                int C) {
    int b = blockIdx.x;
    int lane = threadIdx.x;
    int s = ss[b], e = se[b];
    float acc = 0.0f;
    for (int v = s; v < e; ++v) acc += h[(size_t)v * 64 + lane];
    int cnt = e - s;
    if (cnt < 1) cnt = 1;                        // max(cnt,1); empty graph -> acc stays 0
    float pooled = acc / (float)cnt;
    for (int c = 0; c < C; ++c) {
        float tt = pooled * Wl[lane * C + c];
        for (int off = 32; off > 0; off >>= 1) tt += __shfl_down(tt, off);
        if (lane == 0) out[b * C + c] = tt + bl[c];
    }
}

// ---------------- launch ----------------

extern "C" void kernel_launch(void* const* d_in, const int* in_sizes, int n_in,
                              void* d_out, int out_size, void* d_ws, size_t ws_size,
                              hipStream_t stream) {
    const float* x    = (const float*)d_in[0];
    const int*   ei   = (const int*)d_in[1];
    const int*   batch= (const int*)d_in[2];
    const float* W1   = (const float*)d_in[3];
    const float* b1   = (const float*)d_in[4];
    const float* W2   = (const float*)d_in[5];
    const float* b2   = (const float*)d_in[6];
    const float* W3   = (const float*)d_in[7];
    const float* b3   = (const float*)d_in[8];
    const float* Wl   = (const float*)d_in[9];
    const float* bl   = (const float*)d_in[10];
    float* out = (float*)d_out;

    const int N = in_sizes[2];          // 50000
    const int E = in_sizes[1] / 2;      // 800000
    const int F = in_sizes[0] / N;      // 128
    const int C = 10;
    const int B = out_size / C;         // 512

    char* ws = (char*)d_ws;
    auto alloc = [&](size_t bytes) {
        char* p = ws;
        ws += (bytes + 255) & ~(size_t)255;
        return p;
    };
    float* dinv    = (float*)alloc((size_t)N * 4);
    int*   deg     = (int*)alloc((size_t)N * 4);
    int*   offs    = (int*)alloc((size_t)N * 4);
    int*   cursor  = (int*)alloc((size_t)N * 4);
    int*   bsum    = (int*)alloc(256 * 4);
    int*   segs    = (int*)alloc((size_t)B * 4);
    int*   sege    = (int*)alloc((size_t)B * 4);
    int*   ssrc    = (int*)alloc((size_t)E * 4);
    float* bufA    = (float*)alloc((size_t)N * 64 * 4);
    float* bufB    = (float*)alloc((size_t)N * 64 * 4);

    const int* src = ei;
    const int* dst = ei + E;

    hipMemsetAsync(deg, 0, (size_t)N * 4, stream);
    hipMemsetAsync(segs, 0x7f, (size_t)B * 4, stream);  // ~INT_MAX for atomicMin
    hipMemsetAsync(sege, 0, (size_t)B * 4, stream);

    int nbE = (E + 255) / 256;
    int nbN = (N + 255) / 256;

    k_hist<<<nbE, 256, 0, stream>>>(dst, deg, E);
    k_seg_bounds<<<nbN, 256, 0, stream>>>(batch, segs, sege, N);
    k_scan_part<<<nbN, 256, 0, stream>>>(deg, offs, bsum, N);
    k_scan_blk<<<1, 256, 0, stream>>>(bsum, nbN);
    k_finalize<<<nbN, 256, 0, stream>>>(offs, bsum, deg, dinv, cursor, N);
    k_scatter<<<nbE, 256, 0, stream>>>(src, dst, cursor, ssrc, E);

    int gGemm = (N + 63) / 64;
    int gAgg  = (N + 3) / 4;

    // layer 1: x[N,128] @ W1 -> relu(agg)
    k_gemm_tile<128><<<gGemm, 256, 0, stream>>>(x, W1, dinv, bufA, N);
    k_aggregate<<<gAgg, 256, 0, stream>>>(bufA, ssrc, offs, deg, dinv, b1, bufB, N, 1);
    // layer 2
    k_gemm_tile<64><<<gGemm, 256, 0, stream>>>(bufB, W2, dinv, bufA, N);
    k_aggregate<<<gAgg, 256, 0, stream>>>(bufA, ssrc, offs, deg, dinv, b2, bufB, N, 1);
    // layer 3 (no relu)
    k_gemm_tile<64><<<gGemm, 256, 0, stream>>>(bufB, W3, dinv, bufA, N);
    k_aggregate<<<gAgg, 256, 0, stream>>>(bufA, ssrc, offs, deg, dinv, b3, bufB, N, 0);

    // mean-pool per graph + linear head
    k_pool_classify<<<B, 64, 0, stream>>>(bufB, segs, sege, Wl, bl, out, C);
}

// Round 3
// 324.955 us; speedup vs baseline: 1.2923x; 1.0877x over previous
//
#include <hip/hip_runtime.h>

#define NBSHIFT 8   // 256 nodes per dst-bucket

// ---------------- CSR construction ----------------

__global__ void k_hist(const int* __restrict__ dst, int* __restrict__ deg, int E) {
    int i = blockIdx.x * blockDim.x + threadIdx.x;
    if (i < E) atomicAdd(&deg[dst[i]], 1);
}

__global__ void k_seg_bounds(const int* __restrict__ batch, int* __restrict__ ss,
                             int* __restrict__ se, int N) {
    int i = blockIdx.x * blockDim.x + threadIdx.x;
    if (i < N) {
        int b = batch[i];
        atomicMin(&ss[b], i);
        atomicMax(&se[b], i + 1);
    }
}

__global__ void k_scan_part(const int* __restrict__ deg, int* __restrict__ offs,
                            int* __restrict__ bsum, int N) {
    __shared__ int sd[256];
    int t = threadIdx.x;
    int i = blockIdx.x * 256 + t;
    int v = (i < N) ? deg[i] : 0;
    sd[t] = v;
    __syncthreads();
    int sum = v;
    for (int d = 1; d < 256; d <<= 1) {
        int add = (t >= d) ? sd[t - d] : 0;
        __syncthreads();
        sum += add;
        sd[t] = sum;
        __syncthreads();
    }
    if (i < N) offs[i] = sum - v;              // exclusive within block
    if (t == 255) bsum[blockIdx.x] = sum;      // block total
}

__global__ void k_scan_blk(int* __restrict__ bsum, int nb) {
    __shared__ int sd[256];
    int t = threadIdx.x;
    int v = (t < nb) ? bsum[t] : 0;
    sd[t] = v;
    __syncthreads();
    int sum = v;
    for (int d = 1; d < 256; d <<= 1) {
        int add = (t >= d) ? sd[t - d] : 0;
        __syncthreads();
        sum += add;
        sd[t] = sum;
        __syncthreads();
    }
    if (t < nb) bsum[t] = sum - v;             // exclusive block prefix
}

__global__ void k_finalize(int* __restrict__ offs, const int* __restrict__ bsum,
                           const int* __restrict__ deg, float* __restrict__ dinv,
                           int* __restrict__ cursor, int N) {
    int i = blockIdx.x * blockDim.x + threadIdx.x;
    if (i < N) {
        int o = offs[i] + bsum[i >> 8];
        offs[i] = o;
        cursor[i] = o;
        dinv[i] = rsqrtf((float)deg[i] + 1.0f);   // deg + 1 self-loop
    }
}

// bbase[b] = CSR offset of first node in bucket b; bcur = running cursor for pass 1.
__global__ void k_bucket_base(const int* __restrict__ offs, int* __restrict__ bbase,
                              int* __restrict__ bcur, int N, int NB, int E) {
    int b = blockIdx.x * blockDim.x + threadIdx.x;
    if (b < NB) {
        int v = b << NBSHIFT;
        int o = offs[v];
        bbase[b] = o;
        bcur[b] = o;
    }
    if (b == NB) bbase[NB] = E;
}

// Pass 1: partition edges into dst-buckets (localized pair writes).
__global__ __launch_bounds__(256) void k_bucket_bin(const int* __restrict__ src,
                                                    const int* __restrict__ dst,
                                                    int* __restrict__ bcur,
                                                    int2* __restrict__ pairbuf,
                                                    int E, int NB) {
    __shared__ int lcnt[256];
    __shared__ int lbase[256];
    int t = threadIdx.x;
    int e0 = blockIdx.x * 4096;
    int e1 = min(e0 + 4096, E);
    if (t < 256) lcnt[t] = 0;
    __syncthreads();
    for (int i = e0 + t; i < e1; i += 256)
        atomicAdd(&lcnt[dst[i] >> NBSHIFT], 1);
    __syncthreads();
    if (t < NB) {
        int c = lcnt[t];
        lbase[t] = c ? atomicAdd(&bcur[t], c) : 0;
        lcnt[t] = 0;
    }
    __syncthreads();
    for (int i = e0 + t; i < e1; i += 256) {
        int d = dst[i];
        int b = d >> NBSHIFT;
        int pos = lbase[b] + atomicAdd(&lcnt[b], 1);
        pairbuf[pos] = make_int2(src[i], d);
    }
}

// Pass 2: one block per bucket — exact CSR scatter confined to a ~16KB window
// touched by a single CU (single XCD L2), so lines absorb all writes.
__global__ __launch_bounds__(256) void k_bucket_scatter(const int2* __restrict__ pairbuf,
                                                        const int* __restrict__ bbase,
                                                        int* __restrict__ cursor,
                                                        int* __restrict__ ssrc, int NB) {
    int b = blockIdx.x;
    int s0 = bbase[b], s1 = bbase[b + 1];
    for (int i = s0 + threadIdx.x; i < s1; i += 256) {
        int2 p = pairbuf[i];
        int pos = atomicAdd(&cursor[p.y], 1);
        ssrc[pos] = p.x;
    }
}

// ---------------- per-layer compute ----------------

// out[v][f] = (in[v] @ W)[f] * dinv[v];  in: [N,K], W: [K,64], out: [N,64]
template <int K>
__global__ __launch_bounds__(256) void k_gemm_tile(const float* __restrict__ in,
                                                   const float* __restrict__ W,
                                                   const float* __restrict__ dinv,
                                                   float* __restrict__ out, int N) {
    __shared__ float sX[K][64];
    __shared__ float sW[K][64];
    int t = threadIdx.x;
    int w = t >> 6, l = t & 63;
    int node0 = blockIdx.x * 64;

    for (int i = t; i < K * 16; i += 256)
        ((float4*)&sW[0][0])[i] = ((const float4*)W)[i];

    {
        int node = node0 + l;
        bool ok = node < N;
        const float* rp = in + (size_t)node * K;
        for (int k0 = w * (K / 4); k0 < (w + 1) * (K / 4); k0 += 4) {
            float4 v = ok ? *(const float4*)(rp + k0) : make_float4(0.f, 0.f, 0.f, 0.f);
            sX[k0 + 0][l] = v.x;
            sX[k0 + 1][l] = v.y;
            sX[k0 + 2][l] = v.z;
            sX[k0 + 3][l] = v.w;
        }
    }
    __syncthreads();

    int fg  = l & 15;
    int ngl = w * 4 + (l >> 4);

    float4 a0 = {0.f, 0.f, 0.f, 0.f};
    float4 a1 = {0.f, 0.f, 0.f, 0.f};
    float4 a2 = {0.f, 0.f, 0.f, 0.f};
    float4 a3 = {0.f, 0.f, 0.f, 0.f};

#pragma unroll 8
    for (int k = 0; k < K; ++k) {
        float4 xv = *(const float4*)(&sX[k][ngl * 4]);
        float4 wv = *(const float4*)(&sW[k][fg * 4]);
        a0.x += xv.x * wv.x; a0.y += xv.x * wv.y; a0.z += xv.x * wv.z; a0.w += xv.x * wv.w;
        a1.x += xv.y * wv.x; a1.y += xv.y * wv.y; a1.z += xv.y * wv.z; a1.w += xv.y * wv.w;
        a2.x += xv.z * wv.x; a2.y += xv.z * wv.y; a2.z += xv.z * wv.z; a2.w += xv.z * wv.w;
        a3.x += xv.w * wv.x; a3.y += xv.w * wv.y; a3.z += xv.w * wv.z; a3.w += xv.w * wv.w;
    }

    int nbase = node0 + ngl * 4;
    float4 accs[4] = {a0, a1, a2, a3};
#pragma unroll
    for (int i = 0; i < 4; ++i) {
        int n = nbase + i;
        if (n < N) {
            float s = dinv[n];
            float4 o = accs[i];
            o.x *= s; o.y *= s; o.z *= s; o.w *= s;
            *(float4*)(out + (size_t)n * 64 + fg * 4) = o;
        }
    }
}

// one wave per node; lane = g*16+fl; subgroup g gathers row j+g as float4 ->
// 4 rows per load instruction; shfl_xor(16,32) butterfly merges subgroups.
__global__ __launch_bounds__(256) void k_aggregate4(const float* __restrict__ hs,
                                                    const int* __restrict__ ssrc,
                                                    const int* __restrict__ offs,
                                                    const int* __restrict__ deg,
                                                    const float* __restrict__ dinv,
                                                    const float* __restrict__ bias,
                                                    float* __restrict__ out, int N,
                                                    int do_relu) {
    int t = threadIdx.x;
    int wave = t >> 6, lane = t & 63;
    int g = lane >> 4, fl = lane & 15;
    int v = blockIdx.x * 4 + wave;
    if (v >= N) return;
    int start = offs[v];
    int cnt = deg[v];

    float4 acc = {0.f, 0.f, 0.f, 0.f};
    if (g == 0) acc = *(const float4*)(hs + (size_t)v * 64 + fl * 4);  // self-loop

    int cnt4 = cnt & ~3;
#pragma unroll 2
    for (int j = 0; j < cnt4; j += 4) {
        int s = ssrc[start + j + g];
        float4 h = *(const float4*)(hs + (size_t)s * 64 + fl * 4);
        acc.x += h.x; acc.y += h.y; acc.z += h.z; acc.w += h.w;
    }
    int rem = cnt - cnt4;
    if (g < rem) {
        int s = ssrc[start + cnt4 + g];
        float4 h = *(const float4*)(hs + (size_t)s * 64 + fl * 4);
        acc.x += h.x; acc.y += h.y; acc.z += h.z; acc.w += h.w;
    }

    acc.x += __shfl_xor(acc.x, 16); acc.y += __shfl_xor(acc.y, 16);
    acc.z += __shfl_xor(acc.z, 16); acc.w += __shfl_xor(acc.w, 16);
    acc.x += __shfl_xor(acc.x, 32); acc.y += __shfl_xor(acc.y, 32);
    acc.z += __shfl_xor(acc.z, 32); acc.w += __shfl_xor(acc.w, 32);

    if (g == 0) {
        float s = dinv[v];
        float4 bv = *(const float4*)(bias + fl * 4);
        float4 o;
        o.x = acc.x * s + bv.x;
        o.y = acc.y * s + bv.y;
        o.z = acc.z * s + bv.z;
        o.w = acc.w * s + bv.w;
        if (do_relu) {
            o.x = fmaxf(o.x, 0.f); o.y = fmaxf(o.y, 0.f);
            o.z = fmaxf(o.z, 0.f); o.w = fmaxf(o.w, 0.f);
        }
        *(float4*)(out + (size_t)v * 64 + fl * 4) = o;
    }
}

// one block (64 threads = 1 wave) per graph: mean-pool its node range, then 64x10 head.
__global__ void k_pool_classify(const float* __restrict__ h, const int* __restrict__ ss,
                                const int* __restrict__ se, const float* __restrict__ Wl,
                                const float* __restrict__ bl, float* __restrict__ out,
                                int C) {
    int b = blockIdx.x;
    int lane = threadIdx.x;
    int s = ss[b], e = se[b];
    float acc = 0.0f;
    for (int v = s; v < e; ++v) acc += h[(size_t)v * 64 + lane];
    int cnt = e - s;
    if (cnt < 1) cnt = 1;
    float pooled = acc / (float)cnt;
    for (int c = 0; c < C; ++c) {
        float tt = pooled * Wl[lane * C + c];
        for (int off = 32; off > 0; off >>= 1) tt += __shfl_down(tt, off);
        if (lane == 0) out[b * C + c] = tt + bl[c];
    }
}

// ---------------- launch ----------------

extern "C" void kernel_launch(void* const* d_in, const int* in_sizes, int n_in,
                              void* d_out, int out_size, void* d_ws, size_t ws_size,
                              hipStream_t stream) {
    const float* x    = (const float*)d_in[0];
    const int*   ei   = (const int*)d_in[1];
    const int*   batch= (const int*)d_in[2];
    const float* W1   = (const float*)d_in[3];
    const float* b1   = (const float*)d_in[4];
    const float* W2   = (const float*)d_in[5];
    const float* b2   = (const float*)d_in[6];
    const float* W3   = (const float*)d_in[7];
    const float* b3   = (const float*)d_in[8];
    const float* Wl   = (const float*)d_in[9];
    const float* bl   = (const float*)d_in[10];
    float* out = (float*)d_out;

    const int N = in_sizes[2];          // 50000
    const int E = in_sizes[1] / 2;      // 800000
    const int F = in_sizes[0] / N;      // 128
    const int C = 10;
    const int B = out_size / C;         // 512
    const int NB = (N + (1 << NBSHIFT) - 1) >> NBSHIFT;   // 196 buckets

    char* ws = (char*)d_ws;
    auto alloc = [&](size_t bytes) {
        char* p = ws;
        ws += (bytes + 255) & ~(size_t)255;
        return p;
    };
    float* dinv    = (float*)alloc((size_t)N * 4);
    int*   deg     = (int*)alloc((size_t)N * 4);
    int*   offs    = (int*)alloc((size_t)N * 4);
    int*   cursor  = (int*)alloc((size_t)N * 4);
    int*   bsum    = (int*)alloc(256 * 4);
    int*   segs    = (int*)alloc((size_t)B * 4);
    int*   sege    = (int*)alloc((size_t)B * 4);
    int*   bbase   = (int*)alloc((size_t)(NB + 1) * 4);
    int*   bcur    = (int*)alloc((size_t)NB * 4);
    int*   ssrc    = (int*)alloc((size_t)E * 4);
    float* bufA    = (float*)alloc((size_t)N * 64 * 4);
    float* bufB    = (float*)alloc((size_t)N * 64 * 4);
    // pairbuf (E * 8B = 6.4MB) aliases bufA (12.8MB): dead before first GEMM
    // writes bufA; same-stream ordering guarantees pass-2 consumed it first.
    int2*  pairbuf = (int2*)bufA;

    const int* src = ei;
    const int* dst = ei + E;

    hipMemsetAsync(deg, 0, (size_t)N * 4, stream);
    hipMemsetAsync(segs, 0x7f, (size_t)B * 4, stream);
    hipMemsetAsync(sege, 0, (size_t)B * 4, stream);

    int nbE = (E + 255) / 256;
    int nbN = (N + 255) / 256;

    k_hist<<<nbE, 256, 0, stream>>>(dst, deg, E);
    k_seg_bounds<<<nbN, 256, 0, stream>>>(batch, segs, sege, N);
    k_scan_part<<<nbN, 256, 0, stream>>>(deg, offs, bsum, N);
    k_scan_blk<<<1, 256, 0, stream>>>(bsum, nbN);
    k_finalize<<<nbN, 256, 0, stream>>>(offs, bsum, deg, dinv, cursor, N);
    k_bucket_base<<<(NB + 256) / 256, 256, 0, stream>>>(offs, bbase, bcur, N, NB, E);
    k_bucket_bin<<<(E + 4095) / 4096, 256, 0, stream>>>(src, dst, bcur, pairbuf, E, NB);
    k_bucket_scatter<<<NB, 256, 0, stream>>>(pairbuf, bbase, cursor, ssrc, NB);

    int gGemm = (N + 63) / 64;
    int gAgg  = (N + 3) / 4;

    // layer 1: x[N,128] @ W1 -> relu(agg)
    k_gemm_tile<128><<<gGemm, 256, 0, stream>>>(x, W1, dinv, bufA, N);
    k_aggregate4<<<gAgg, 256, 0, stream>>>(bufA, ssrc, offs, deg, dinv, b1, bufB, N, 1);
    // layer 2
    k_gemm_tile<64><<<gGemm, 256, 0, stream>>>(bufB, W2, dinv, bufA, N);
    k_aggregate4<<<gAgg, 256, 0, stream>>>(bufA, ssrc, offs, deg, dinv, b2, bufB, N, 1);
    // layer 3 (no relu)
    k_gemm_tile<64><<<gGemm, 256, 0, stream>>>(bufB, W3, dinv, bufA, N);
    k_aggregate4<<<gAgg, 256, 0, stream>>>(bufA, ssrc, offs, deg, dinv, b3, bufB, N, 0);

    // mean-pool per graph + linear head
    k_pool_classify<<<B, 64, 0, stream>>>(bufB, segs, sege, Wl, bl, out, C);
}

// Round 4
// 216.313 us; speedup vs baseline: 1.9413x; 1.5022x over previous
//
#include <hip/hip_runtime.h>

#define NBSHIFT 8   // 256 nodes per dst-bucket
#define CHUNK 4096  // edges per binning block

// ---------------- CSR construction (bucket pipeline, no global atomics on nodes) ----

// count bucket sizes: LDS-aggregated histogram of dst>>8
__global__ __launch_bounds__(256) void k_count(const int* __restrict__ dst,
                                               int* __restrict__ bcnt, int E, int NB) {
    __shared__ int lcnt[256];
    int t = threadIdx.x;
    int e0 = blockIdx.x * CHUNK;
    int e1 = min(e0 + CHUNK, E);
    lcnt[t] = 0;
    __syncthreads();
    for (int i = e0 + t; i < e1; i += 256)
        atomicAdd(&lcnt[dst[i] >> NBSHIFT], 1);
    __syncthreads();
    if (t < NB && lcnt[t]) atomicAdd(&bcnt[t], lcnt[t]);
}

// single block: exclusive scan of bucket counts -> bbase/bcur; offs[N]=E
__global__ __launch_bounds__(256) void k_bucket_scan(const int* __restrict__ bcnt,
                                                     int* __restrict__ bbase,
                                                     int* __restrict__ bcur,
                                                     int* __restrict__ offs,
                                                     int NB, int N, int E) {
    __shared__ int sd[256];
    int t = threadIdx.x;
    int v = (t < NB) ? bcnt[t] : 0;
    sd[t] = v;
    __syncthreads();
    int sum = v;
    for (int d = 1; d < 256; d <<= 1) {
        int add = (t >= d) ? sd[t - d] : 0;
        __syncthreads();
        sum += add;
        sd[t] = sum;
        __syncthreads();
    }
    int excl = sum - v;
    if (t <= NB) bbase[t] = excl;     // at t==NB: v=0, sum=E -> bbase[NB]=E
    if (t < NB) bcur[t] = excl;
    if (t == 0) offs[N] = E;
}

// partition edges into dst-buckets; pair packed to 4B: (dst&255)<<24 | src
__global__ __launch_bounds__(256) void k_bin(const int* __restrict__ src,
                                             const int* __restrict__ dst,
                                             int* __restrict__ bcur,
                                             unsigned* __restrict__ pairbuf,
                                             int E, int NB) {
    __shared__ int lcnt[256];
    __shared__ int lbase[256];
    int t = threadIdx.x;
    int e0 = blockIdx.x * CHUNK;
    int e1 = min(e0 + CHUNK, E);
    lcnt[t] = 0;
    __syncthreads();
    for (int i = e0 + t; i < e1; i += 256)
        atomicAdd(&lcnt[dst[i] >> NBSHIFT], 1);
    __syncthreads();
    if (t < NB) {
        int c = lcnt[t];
        lbase[t] = c ? atomicAdd(&bcur[t], c) : 0;
        lcnt[t] = 0;
    }
    __syncthreads();
    for (int i = e0 + t; i < e1; i += 256) {
        int d = dst[i];
        int b = d >> NBSHIFT;
        int pos = lbase[b] + atomicAdd(&lcnt[b], 1);
        pairbuf[pos] = ((unsigned)(d & 255) << 24) | (unsigned)src[i];
    }
}

// one block per bucket: LDS histogram -> deg; LDS scan -> offs; LDS cursors -> ssrc.
// All writes confined to this bucket's contiguous CSR window; LDS atomics only.
__global__ __launch_bounds__(256) void k_build(const unsigned* __restrict__ pairbuf,
                                               const int* __restrict__ bbase,
                                               int* __restrict__ offs,
                                               float* __restrict__ dinv,
                                               int* __restrict__ ssrc, int N) {
    __shared__ int cnt[256];
    __shared__ int sd[256];
    __shared__ int cur[256];
    int b = blockIdx.x;
    int t = threadIdx.x;
    int s0 = bbase[b], s1 = bbase[b + 1];
    cnt[t] = 0;
    __syncthreads();
    for (int i = s0 + t; i < s1; i += 256)
        atomicAdd(&cnt[pairbuf[i] >> 24], 1);
    __syncthreads();
    int v = cnt[t];
    sd[t] = v;
    __syncthreads();
    int sum = v;
    for (int d = 1; d < 256; d <<= 1) {
        int add = (t >= d) ? sd[t - d] : 0;
        __syncthreads();
        sum += add;
        sd[t] = sum;
        __syncthreads();
    }
    int excl = sum - v;
    int node = (b << NBSHIFT) + t;
    if (node < N) {
        offs[node] = s0 + excl;
        dinv[node] = rsqrtf((float)v + 1.0f);   // deg + 1 self-loop
    }
    cur[t] = s0 + excl;
    __syncthreads();
    for (int i = s0 + t; i < s1; i += 256) {
        unsigned p = pairbuf[i];
        int pos = atomicAdd(&cur[p >> 24], 1);
        ssrc[pos] = (int)(p & 0x00FFFFFFu);
    }
}

// batch is sorted: boundary detection, no atomics. ss/se pre-zeroed (empty graphs -> 0,0).
__global__ void k_seg2(const int* __restrict__ batch, int* __restrict__ ss,
                       int* __restrict__ se, int N) {
    int i = blockIdx.x * blockDim.x + threadIdx.x;
    if (i == 0) ss[batch[0]] = 0;
    if (i == N - 1) se[batch[N - 1]] = N;
    if (i < N - 1) {
        int b0 = batch[i], b1 = batch[i + 1];
        if (b0 != b1) { se[b0] = i + 1; ss[b1] = i + 1; }
    }
}

// ---------------- per-layer compute ----------------

// out[v][f] = (in[v] @ W)[f] * dinv[v];  in: [N,K], W: [K,64], out: [N,64]
template <int K>
__global__ __launch_bounds__(256) void k_gemm_tile(const float* __restrict__ in,
                                                   const float* __restrict__ W,
                                                   const float* __restrict__ dinv,
                                                   float* __restrict__ out, int N) {
    __shared__ float sX[K][64];
    __shared__ float sW[K][64];
    int t = threadIdx.x;
    int w = t >> 6, l = t & 63;
    int node0 = blockIdx.x * 64;

    for (int i = t; i < K * 16; i += 256)
        ((float4*)&sW[0][0])[i] = ((const float4*)W)[i];

    {
        int node = node0 + l;
        bool ok = node < N;
        const float* rp = in + (size_t)node * K;
        for (int k0 = w * (K / 4); k0 < (w + 1) * (K / 4); k0 += 4) {
            float4 v = ok ? *(const float4*)(rp + k0) : make_float4(0.f, 0.f, 0.f, 0.f);
            sX[k0 + 0][l] = v.x;
            sX[k0 + 1][l] = v.y;
            sX[k0 + 2][l] = v.z;
            sX[k0 + 3][l] = v.w;
        }
    }
    __syncthreads();

    int fg  = l & 15;
    int ngl = w * 4 + (l >> 4);

    float4 a0 = {0.f, 0.f, 0.f, 0.f};
    float4 a1 = {0.f, 0.f, 0.f, 0.f};
    float4 a2 = {0.f, 0.f, 0.f, 0.f};
    float4 a3 = {0.f, 0.f, 0.f, 0.f};

#pragma unroll 8
    for (int k = 0; k < K; ++k) {
        float4 xv = *(const float4*)(&sX[k][ngl * 4]);
        float4 wv = *(const float4*)(&sW[k][fg * 4]);
        a0.x += xv.x * wv.x; a0.y += xv.x * wv.y; a0.z += xv.x * wv.z; a0.w += xv.x * wv.w;
        a1.x += xv.y * wv.x; a1.y += xv.y * wv.y; a1.z += xv.y * wv.z; a1.w += xv.y * wv.w;
        a2.x += xv.z * wv.x; a2.y += xv.z * wv.y; a2.z += xv.z * wv.z; a2.w += xv.z * wv.w;
        a3.x += xv.w * wv.x; a3.y += xv.w * wv.y; a3.z += xv.w * wv.z; a3.w += xv.w * wv.w;
    }

    int nbase = node0 + ngl * 4;
    float4 accs[4] = {a0, a1, a2, a3};
#pragma unroll
    for (int i = 0; i < 4; ++i) {
        int n = nbase + i;
        if (n < N) {
            float s = dinv[n];
            float4 o = accs[i];
            o.x *= s; o.y *= s; o.z *= s; o.w *= s;
            *(float4*)(out + (size_t)n * 64 + fg * 4) = o;
        }
    }
}

// one wave per node; lane = g*16+fl; subgroup g gathers row j+g as float4 ->
// 4 rows per load instruction; shfl_xor(16,32) butterfly merges subgroups.
__global__ __launch_bounds__(256) void k_aggregate4(const float* __restrict__ hs,
                                                    const int* __restrict__ ssrc,
                                                    const int* __restrict__ offs,
                                                    const float* __restrict__ dinv,
                                                    const float* __restrict__ bias,
                                                    float* __restrict__ out, int N,
                                                    int do_relu) {
    int t = threadIdx.x;
    int wave = t >> 6, lane = t & 63;
    int g = lane >> 4, fl = lane & 15;
    int v = blockIdx.x * 4 + wave;
    if (v >= N) return;
    int start = offs[v];
    int cnt = offs[v + 1] - start;

    float4 acc = {0.f, 0.f, 0.f, 0.f};
    if (g == 0) acc = *(const float4*)(hs + (size_t)v * 64 + fl * 4);  // self-loop

    int cnt4 = cnt & ~3;
#pragma unroll 2
    for (int j = 0; j < cnt4; j += 4) {
        int s = ssrc[start + j + g];
        float4 h = *(const float4*)(hs + (size_t)s * 64 + fl * 4);
        acc.x += h.x; acc.y += h.y; acc.z += h.z; acc.w += h.w;
    }
    int rem = cnt - cnt4;
    if (g < rem) {
        int s = ssrc[start + cnt4 + g];
        float4 h = *(const float4*)(hs + (size_t)s * 64 + fl * 4);
        acc.x += h.x; acc.y += h.y; acc.z += h.z; acc.w += h.w;
    }

    acc.x += __shfl_xor(acc.x, 16); acc.y += __shfl_xor(acc.y, 16);
    acc.z += __shfl_xor(acc.z, 16); acc.w += __shfl_xor(acc.w, 16);
    acc.x += __shfl_xor(acc.x, 32); acc.y += __shfl_xor(acc.y, 32);
    acc.z += __shfl_xor(acc.z, 32); acc.w += __shfl_xor(acc.w, 32);

    if (g == 0) {
        float s = dinv[v];
        float4 bv = *(const float4*)(bias + fl * 4);
        float4 o;
        o.x = acc.x * s + bv.x;
        o.y = acc.y * s + bv.y;
        o.z = acc.z * s + bv.z;
        o.w = acc.w * s + bv.w;
        if (do_relu) {
            o.x = fmaxf(o.x, 0.f); o.y = fmaxf(o.y, 0.f);
            o.z = fmaxf(o.z, 0.f); o.w = fmaxf(o.w, 0.f);
        }
        *(float4*)(out + (size_t)v * 64 + fl * 4) = o;
    }
}

// one wave per graph: 4 nodes in flight (g-split), float4 per lane; then 64x10 head.
__global__ __launch_bounds__(64) void k_pool_classify(const float* __restrict__ h,
                                                      const int* __restrict__ ss,
                                                      const int* __restrict__ se,
                                                      const float* __restrict__ Wl,
                                                      const float* __restrict__ bl,
                                                      float* __restrict__ out, int C) {
    int b = blockIdx.x;
    int lane = threadIdx.x;
    int g = lane >> 4, fl = lane & 15;
    int s = ss[b], e = se[b];
    float4 acc = {0.f, 0.f, 0.f, 0.f};
#pragma unroll 2
    for (int v = s + g; v < e; v += 4) {
        float4 hv = *(const float4*)(h + (size_t)v * 64 + fl * 4);
        acc.x += hv.x; acc.y += hv.y; acc.z += hv.z; acc.w += hv.w;
    }
    acc.x += __shfl_xor(acc.x, 16); acc.y += __shfl_xor(acc.y, 16);
    acc.z += __shfl_xor(acc.z, 16); acc.w += __shfl_xor(acc.w, 16);
    acc.x += __shfl_xor(acc.x, 32); acc.y += __shfl_xor(acc.y, 32);
    acc.z += __shfl_xor(acc.z, 32); acc.w += __shfl_xor(acc.w, 32);

    if (g == 0) {
        int cnt = e - s;
        if (cnt < 1) cnt = 1;
        float inv = 1.0f / (float)cnt;
        float4 p;
        p.x = acc.x * inv; p.y = acc.y * inv; p.z = acc.z * inv; p.w = acc.w * inv;
        int f0 = fl * 4;
        for (int c = 0; c < C; ++c) {
            float tt = p.x * Wl[(f0 + 0) * C + c] + p.y * Wl[(f0 + 1) * C + c]
                     + p.z * Wl[(f0 + 2) * C + c] + p.w * Wl[(f0 + 3) * C + c];
            tt += __shfl_xor(tt, 1); tt += __shfl_xor(tt, 2);
            tt += __shfl_xor(tt, 4); tt += __shfl_xor(tt, 8);
            if (fl == 0) out[b * C + c] = tt + bl[c];
        }
    }
}

// ---------------- launch ----------------

extern "C" void kernel_launch(void* const* d_in, const int* in_sizes, int n_in,
                              void* d_out, int out_size, void* d_ws, size_t ws_size,
                              hipStream_t stream) {
    const float* x    = (const float*)d_in[0];
    const int*   ei   = (const int*)d_in[1];
    const int*   batch= (const int*)d_in[2];
    const float* W1   = (const float*)d_in[3];
    const float* b1   = (const float*)d_in[4];
    const float* W2   = (const float*)d_in[5];
    const float* b2   = (const float*)d_in[6];
    const float* W3   = (const float*)d_in[7];
    const float* b3   = (const float*)d_in[8];
    const float* Wl   = (const float*)d_in[9];
    const float* bl   = (const float*)d_in[10];
    float* out = (float*)d_out;

    const int N = in_sizes[2];          // 50000
    const int E = in_sizes[1] / 2;      // 800000
    const int C = 10;
    const int B = out_size / C;         // 512
    const int NB = (N + (1 << NBSHIFT) - 1) >> NBSHIFT;   // 196 buckets

    char* ws = (char*)d_ws;
    auto alloc = [&](size_t bytes) {
        char* p = ws;
        ws += (bytes + 255) & ~(size_t)255;
        return p;
    };
    float* dinv    = (float*)alloc((size_t)N * 4);
    int*   offs    = (int*)alloc((size_t)(N + 1) * 4);
    int*   bcnt    = (int*)alloc((size_t)NB * 4);
    int*   bbase   = (int*)alloc((size_t)(NB + 1) * 4);
    int*   bcur    = (int*)alloc((size_t)NB * 4);
    int*   segs    = (int*)alloc((size_t)B * 4);
    int*   sege    = (int*)alloc((size_t)B * 4);
    int*   ssrc    = (int*)alloc((size_t)E * 4);
    float* bufA    = (float*)alloc((size_t)N * 64 * 4);
    float* bufB    = (float*)alloc((size_t)N * 64 * 4);
    // pairbuf (E * 4B = 3.2MB) aliases bufA (12.8MB): consumed by k_build before
    // the first GEMM writes bufA (same-stream ordering).
    unsigned* pairbuf = (unsigned*)bufA;

    const int* src = ei;
    const int* dst = ei + E;

    hipMemsetAsync(bcnt, 0, (size_t)NB * 4, stream);
    hipMemsetAsync(segs, 0, (size_t)B * 4, stream);
    hipMemsetAsync(sege, 0, (size_t)B * 4, stream);

    int nbChunk = (E + CHUNK - 1) / CHUNK;
    int nbN = (N + 255) / 256;

    k_count<<<nbChunk, 256, 0, stream>>>(dst, bcnt, E, NB);
    k_bucket_scan<<<1, 256, 0, stream>>>(bcnt, bbase, bcur, offs, NB, N, E);
    k_bin<<<nbChunk, 256, 0, stream>>>(src, dst, bcur, pairbuf, E, NB);
    k_build<<<NB, 256, 0, stream>>>(pairbuf, bbase, offs, dinv, ssrc, N);
    k_seg2<<<nbN, 256, 0, stream>>>(batch, segs, sege, N);

    int gGemm = (N + 63) / 64;
    int gAgg  = (N + 3) / 4;

    // layer 1: x[N,128] @ W1 -> relu(agg)
    k_gemm_tile<128><<<gGemm, 256, 0, stream>>>(x, W1, dinv, bufA, N);
    k_aggregate4<<<gAgg, 256, 0, stream>>>(bufA, ssrc, offs, dinv, b1, bufB, N, 1);
    // layer 2
    k_gemm_tile<64><<<gGemm, 256, 0, stream>>>(bufB, W2, dinv, bufA, N);
    k_aggregate4<<<gAgg, 256, 0, stream>>>(bufA, ssrc, offs, dinv, b2, bufB, N, 1);
    // layer 3 (no relu)
    k_gemm_tile<64><<<gGemm, 256, 0, stream>>>(bufB, W3, dinv, bufA, N);
    k_aggregate4<<<gAgg, 256, 0, stream>>>(bufA, ssrc, offs, dinv, b3, bufB, N, 0);

    // mean-pool per graph + linear head
    k_pool_classify<<<B, 64, 0, stream>>>(bufB, segs, sege, Wl, bl, out, C);
}

// Round 5
// 209.321 us; speedup vs baseline: 2.0062x; 1.0334x over previous
//
#include <hip/hip_runtime.h>

#define NBSHIFT 8   // 256 nodes per dst-bucket
#define CHUNK 4096  // edges per binning block

// ---------------- CSR construction (bucket pipeline) ----------------

// fused: blocks [0,nbChunk) histogram dst-buckets; blocks [nbChunk,..) do
// segment-boundary detection on the sorted batch array.
__global__ __launch_bounds__(256) void k_count_seg(const int* __restrict__ dst,
                                                   int* __restrict__ bcnt, int E, int NB,
                                                   const int* __restrict__ batch,
                                                   int* __restrict__ ss,
                                                   int* __restrict__ se, int N,
                                                   int nbChunk) {
    __shared__ int lcnt[256];
    int t = threadIdx.x;
    if (blockIdx.x < (unsigned)nbChunk) {
        int e0 = blockIdx.x * CHUNK;
        int e1 = min(e0 + CHUNK, E);
        lcnt[t] = 0;
        __syncthreads();
        for (int i = e0 + t; i < e1; i += 256)
            atomicAdd(&lcnt[dst[i] >> NBSHIFT], 1);
        __syncthreads();
        if (t < NB && lcnt[t]) atomicAdd(&bcnt[t], lcnt[t]);
    } else {
        int i = (blockIdx.x - nbChunk) * 256 + t;
        if (i == 0) ss[batch[0]] = 0;
        if (i == N - 1) se[batch[N - 1]] = N;
        if (i < N - 1) {
            int b0 = batch[i], b1 = batch[i + 1];
            if (b0 != b1) { se[b0] = i + 1; ss[b1] = i + 1; }
        }
    }
}

// partition edges into dst-buckets; pair packed to 4B: (dst&255)<<24 | src.
// bucket bases recomputed in-block from bcnt (196-wide scan — avoids a
// separate 1-block scan launch); allocation via zeroed bcur0 cursors.
__global__ __launch_bounds__(256) void k_bin(const int* __restrict__ src,
                                             const int* __restrict__ dst,
                                             const int* __restrict__ bcnt,
                                             int* __restrict__ bcur0,
                                             unsigned* __restrict__ pairbuf,
                                             int E, int NB) {
    __shared__ int sd[256];
    __shared__ int lcnt[256];
    __shared__ int lbase[256];
    int t = threadIdx.x;
    int v = (t < NB) ? bcnt[t] : 0;
    sd[t] = v;
    lcnt[t] = 0;
    __syncthreads();
    int sum = v;
    for (int d = 1; d < 256; d <<= 1) {
        int add = (t >= d) ? sd[t - d] : 0;
        __syncthreads();
        sum += add;
        sd[t] = sum;
        __syncthreads();
    }
    int bbase_t = sum - v;            // exclusive scan = bucket base
    int e0 = blockIdx.x * CHUNK;
    int e1 = min(e0 + CHUNK, E);
    for (int i = e0 + t; i < e1; i += 256)
        atomicAdd(&lcnt[dst[i] >> NBSHIFT], 1);
    __syncthreads();
    if (t < NB) {
        int c = lcnt[t];
        lbase[t] = bbase_t + (c ? atomicAdd(&bcur0[t], c) : 0);
        lcnt[t] = 0;
    }
    __syncthreads();
    for (int i = e0 + t; i < e1; i += 256) {
        int d = dst[i];
        int b = d >> NBSHIFT;
        int pos = lbase[b] + atomicAdd(&lcnt[b], 1);
        pairbuf[pos] = ((unsigned)(d & 255) << 24) | (unsigned)src[i];
    }
}

// one block per bucket: recompute base via in-block scan of bcnt, then LDS
// histogram -> deg/dinv, LDS scan -> offs, LDS cursors -> ssrc.
__global__ __launch_bounds__(256) void k_build(const unsigned* __restrict__ pairbuf,
                                               const int* __restrict__ bcnt,
                                               int* __restrict__ offs,
                                               float* __restrict__ dinv,
                                               int* __restrict__ ssrc, int N, int NB,
                                               int E) {
    __shared__ int sd[256];
    __shared__ int sexcl[256];
    __shared__ int cnt[256];
    __shared__ int cur[256];
    int b = blockIdx.x;
    int t = threadIdx.x;
    int v = (t < NB) ? bcnt[t] : 0;
    sd[t] = v;
    cnt[t] = 0;
    __syncthreads();
    int sum = v;
    for (int d = 1; d < 256; d <<= 1) {
        int add = (t >= d) ? sd[t - d] : 0;
        __syncthreads();
        sum += add;
        sd[t] = sum;
        __syncthreads();
    }
    sexcl[t] = sum - v;
    __syncthreads();
    int s0 = sexcl[b];
    int s1 = s0 + ((b < NB) ? bcnt[b] : 0);
    for (int i = s0 + t; i < s1; i += 256)
        atomicAdd(&cnt[pairbuf[i] >> 24], 1);
    __syncthreads();
    int c = cnt[t];
    sd[t] = c;
    __syncthreads();
    int sum2 = c;
    for (int d = 1; d < 256; d <<= 1) {
        int add = (t >= d) ? sd[t - d] : 0;
        __syncthreads();
        sum2 += add;
        sd[t] = sum2;
        __syncthreads();
    }
    int excl2 = sum2 - c;
    int node = (b << NBSHIFT) + t;
    if (node < N) {
        offs[node] = s0 + excl2;
        dinv[node] = rsqrtf((float)c + 1.0f);   // deg + 1 self-loop
    }
    if (b == 0 && t == 0) offs[N] = E;
    cur[t] = s0 + excl2;
    __syncthreads();
    for (int i = s0 + t; i < s1; i += 256) {
        unsigned p = pairbuf[i];
        int pos = atomicAdd(&cur[p >> 24], 1);
        ssrc[pos] = (int)(p & 0x00FFFFFFu);
    }
}

// ---------------- per-layer compute ----------------

// out[v][f] = (in[v] @ W)[f] * dinv[v];  in: [N,K], W: [K,64], out: [N,64]
template <int K>
__global__ __launch_bounds__(256) void k_gemm_tile(const float* __restrict__ in,
                                                   const float* __restrict__ W,
                                                   const float* __restrict__ dinv,
                                                   float* __restrict__ out, int N) {
    __shared__ float sX[K][64];
    __shared__ float sW[K][64];
    int t = threadIdx.x;
    int w = t >> 6, l = t & 63;
    int node0 = blockIdx.x * 64;

    for (int i = t; i < K * 16; i += 256)
        ((float4*)&sW[0][0])[i] = ((const float4*)W)[i];

    {
        int node = node0 + l;
        bool ok = node < N;
        const float* rp = in + (size_t)node * K;
        for (int k0 = w * (K / 4); k0 < (w + 1) * (K / 4); k0 += 4) {
            float4 v = ok ? *(const float4*)(rp + k0) : make_float4(0.f, 0.f, 0.f, 0.f);
            sX[k0 + 0][l] = v.x;
            sX[k0 + 1][l] = v.y;
            sX[k0 + 2][l] = v.z;
            sX[k0 + 3][l] = v.w;
        }
    }
    __syncthreads();

    int fg  = l & 15;
    int ngl = w * 4 + (l >> 4);

    float4 a0 = {0.f, 0.f, 0.f, 0.f};
    float4 a1 = {0.f, 0.f, 0.f, 0.f};
    float4 a2 = {0.f, 0.f, 0.f, 0.f};
    float4 a3 = {0.f, 0.f, 0.f, 0.f};

#pragma unroll 8
    for (int k = 0; k < K; ++k) {
        float4 xv = *(const float4*)(&sX[k][ngl * 4]);
        float4 wv = *(const float4*)(&sW[k][fg * 4]);
        a0.x += xv.x * wv.x; a0.y += xv.x * wv.y; a0.z += xv.x * wv.z; a0.w += xv.x * wv.w;
        a1.x += xv.y * wv.x; a1.y += xv.y * wv.y; a1.z += xv.y * wv.z; a1.w += xv.y * wv.w;
        a2.x += xv.z * wv.x; a2.y += xv.z * wv.y; a2.z += xv.z * wv.z; a2.w += xv.z * wv.w;
        a3.x += xv.w * wv.x; a3.y += xv.w * wv.y; a3.z += xv.w * wv.z; a3.w += xv.w * wv.w;
    }

    int nbase = node0 + ngl * 4;
    float4 accs[4] = {a0, a1, a2, a3};
#pragma unroll
    for (int i = 0; i < 4; ++i) {
        int n = nbase + i;
        if (n < N) {
            float s = dinv[n];
            float4 o = accs[i];
            o.x *= s; o.y *= s; o.z *= s; o.w *= s;
            *(float4*)(out + (size_t)n * 64 + fg * 4) = o;
        }
    }
}

// one wave per node; lane = g*16+fl; 16 rows in flight per iteration
// (each 16-lane subgroup issues 4 independent float4 gathers), then
// shfl_xor(16,32) butterfly merges the 4 subgroups.
__global__ __launch_bounds__(256) void k_aggregate16(const float* __restrict__ hs,
                                                     const int* __restrict__ ssrc,
                                                     const int* __restrict__ offs,
                                                     const float* __restrict__ dinv,
                                                     const float* __restrict__ bias,
                                                     float* __restrict__ out, int N,
                                                     int do_relu) {
    int t = threadIdx.x;
    int wave = t >> 6, lane = t & 63;
    int g = lane >> 4, fl = lane & 15;
    int v = blockIdx.x * 4 + wave;
    if (v >= N) return;
    int start = offs[v];
    int cnt = offs[v + 1] - start;

    float4 acc = {0.f, 0.f, 0.f, 0.f};
    if (g == 0) acc = *(const float4*)(hs + (size_t)v * 64 + fl * 4);  // self-loop

    int j = 0;
    int cnt16 = cnt & ~15;
    for (; j < cnt16; j += 16) {
        int s0 = ssrc[start + j + g];
        int s1 = ssrc[start + j + 4 + g];
        int s2 = ssrc[start + j + 8 + g];
        int s3 = ssrc[start + j + 12 + g];
        float4 h0 = *(const float4*)(hs + (size_t)s0 * 64 + fl * 4);
        float4 h1 = *(const float4*)(hs + (size_t)s1 * 64 + fl * 4);
        float4 h2 = *(const float4*)(hs + (size_t)s2 * 64 + fl * 4);
        float4 h3 = *(const float4*)(hs + (size_t)s3 * 64 + fl * 4);
        acc.x += h0.x; acc.y += h0.y; acc.z += h0.z; acc.w += h0.w;
        acc.x += h1.x; acc.y += h1.y; acc.z += h1.z; acc.w += h1.w;
        acc.x += h2.x; acc.y += h2.y; acc.z += h2.z; acc.w += h2.w;
        acc.x += h3.x; acc.y += h3.y; acc.z += h3.z; acc.w += h3.w;
    }
    int cnt4 = cnt & ~3;
    for (; j < cnt4; j += 4) {
        int s = ssrc[start + j + g];
        float4 h = *(const float4*)(hs + (size_t)s * 64 + fl * 4);
        acc.x += h.x; acc.y += h.y; acc.z += h.z; acc.w += h.w;
    }
    int rem = cnt - cnt4;
    if (g < rem) {
        int s = ssrc[start + cnt4 + g];
        float4 h = *(const float4*)(hs + (size_t)s * 64 + fl * 4);
        acc.x += h.x; acc.y += h.y; acc.z += h.z; acc.w += h.w;
    }

    acc.x += __shfl_xor(acc.x, 16); acc.y += __shfl_xor(acc.y, 16);
    acc.z += __shfl_xor(acc.z, 16); acc.w += __shfl_xor(acc.w, 16);
    acc.x += __shfl_xor(acc.x, 32); acc.y += __shfl_xor(acc.y, 32);
    acc.z += __shfl_xor(acc.z, 32); acc.w += __shfl_xor(acc.w, 32);

    if (g == 0) {
        float s = dinv[v];
        float4 bv = *(const float4*)(bias + fl * 4);
        float4 o;
        o.x = acc.x * s + bv.x;
        o.y = acc.y * s + bv.y;
        o.z = acc.z * s + bv.z;
        o.w = acc.w * s + bv.w;
        if (do_relu) {
            o.x = fmaxf(o.x, 0.f); o.y = fmaxf(o.y, 0.f);
            o.z = fmaxf(o.z, 0.f); o.w = fmaxf(o.w, 0.f);
        }
        *(float4*)(out + (size_t)v * 64 + fl * 4) = o;
    }
}

// one wave per graph: 4 nodes in flight (g-split), float4 per lane; then 64x10 head.
__global__ __launch_bounds__(64) void k_pool_classify(const float* __restrict__ h,
                                                      const int* __restrict__ ss,
                                                      const int* __restrict__ se,
                                                      const float* __restrict__ Wl,
                                                      const float* __restrict__ bl,
                                                      float* __restrict__ out, int C) {
    int b = blockIdx.x;
    int lane = threadIdx.x;
    int g = lane >> 4, fl = lane & 15;
    int s = ss[b], e = se[b];
    float4 acc = {0.f, 0.f, 0.f, 0.f};
#pragma unroll 2
    for (int v = s + g; v < e; v += 4) {
        float4 hv = *(const float4*)(h + (size_t)v * 64 + fl * 4);
        acc.x += hv.x; acc.y += hv.y; acc.z += hv.z; acc.w += hv.w;
    }
    acc.x += __shfl_xor(acc.x, 16); acc.y += __shfl_xor(acc.y, 16);
    acc.z += __shfl_xor(acc.z, 16); acc.w += __shfl_xor(acc.w, 16);
    acc.x += __shfl_xor(acc.x, 32); acc.y += __shfl_xor(acc.y, 32);
    acc.z += __shfl_xor(acc.z, 32); acc.w += __shfl_xor(acc.w, 32);

    if (g == 0) {
        int cnt = e - s;
        if (cnt < 1) cnt = 1;
        float inv = 1.0f / (float)cnt;
        float4 p;
        p.x = acc.x * inv; p.y = acc.y * inv; p.z = acc.z * inv; p.w = acc.w * inv;
        int f0 = fl * 4;
        for (int c = 0; c < C; ++c) {
            float tt = p.x * Wl[(f0 + 0) * C + c] + p.y * Wl[(f0 + 1) * C + c]
                     + p.z * Wl[(f0 + 2) * C + c] + p.w * Wl[(f0 + 3) * C + c];
            tt += __shfl_xor(tt, 1); tt += __shfl_xor(tt, 2);
            tt += __shfl_xor(tt, 4); tt += __shfl_xor(tt, 8);
            if (fl == 0) out[b * C + c] = tt + bl[c];
        }
    }
}

// ---------------- launch ----------------

extern "C" void kernel_launch(void* const* d_in, const int* in_sizes, int n_in,
                              void* d_out, int out_size, void* d_ws, size_t ws_size,
                              hipStream_t stream) {
    const float* x    = (const float*)d_in[0];
    const int*   ei   = (const int*)d_in[1];
    const int*   batch= (const int*)d_in[2];
    const float* W1   = (const float*)d_in[3];
    const float* b1   = (const float*)d_in[4];
    const float* W2   = (const float*)d_in[5];
    const float* b2   = (const float*)d_in[6];
    const float* W3   = (const float*)d_in[7];
    const float* b3   = (const float*)d_in[8];
    const float* Wl   = (const float*)d_in[9];
    const float* bl   = (const float*)d_in[10];
    float* out = (float*)d_out;

    const int N = in_sizes[2];          // 50000
    const int E = in_sizes[1] / 2;      // 800000
    const int C = 10;
    const int B = out_size / C;         // 512
    const int NB = (N + (1 << NBSHIFT) - 1) >> NBSHIFT;   // 196 buckets

    char* ws = (char*)d_ws;
    auto alloc = [&](size_t bytes) {
        char* p = ws;
        ws += (bytes + 255) & ~(size_t)255;
        return p;
    };
    // contiguous zero region: bcnt | bcur0 | segs | sege  (single memset)
    int*   zreg    = (int*)alloc((size_t)(2 * NB + 2 * B) * 4);
    int*   bcnt    = zreg;
    int*   bcur0   = zreg + NB;
    int*   segs    = zreg + 2 * NB;
    int*   sege    = zreg + 2 * NB + B;
    float* dinv    = (float*)alloc((size_t)N * 4);
    int*   offs    = (int*)alloc((size_t)(N + 1) * 4);
    int*   ssrc    = (int*)alloc((size_t)E * 4);
    float* bufA    = (float*)alloc((size_t)N * 64 * 4);
    float* bufB    = (float*)alloc((size_t)N * 64 * 4);
    // pairbuf (E * 4B = 3.2MB) aliases bufA (12.8MB): consumed by k_build before
    // the first GEMM writes bufA (same-stream ordering).
    unsigned* pairbuf = (unsigned*)bufA;

    const int* src = ei;
    const int* dst = ei + E;

    hipMemsetAsync(zreg, 0, (size_t)(2 * NB + 2 * B) * 4, stream);

    int nbChunk = (E + CHUNK - 1) / CHUNK;
    int nbN = (N + 255) / 256;

    k_count_seg<<<nbChunk + nbN, 256, 0, stream>>>(dst, bcnt, E, NB,
                                                   batch, segs, sege, N, nbChunk);
    k_bin<<<nbChunk, 256, 0, stream>>>(src, dst, bcnt, bcur0, pairbuf, E, NB);
    k_build<<<NB, 256, 0, stream>>>(pairbuf, bcnt, offs, dinv, ssrc, N, NB, E);

    int gGemm = (N + 63) / 64;
    int gAgg  = (N + 3) / 4;

    // layer 1: x[N,128] @ W1 -> relu(agg)
    k_gemm_tile<128><<<gGemm, 256, 0, stream>>>(x, W1, dinv, bufA, N);
    k_aggregate16<<<gAgg, 256, 0, stream>>>(bufA, ssrc, offs, dinv, b1, bufB, N, 1);
    // layer 2
    k_gemm_tile<64><<<gGemm, 256, 0, stream>>>(bufB, W2, dinv, bufA, N);
    k_aggregate16<<<gAgg, 256, 0, stream>>>(bufA, ssrc, offs, dinv, b2, bufB, N, 1);
    // layer 3 (no relu)
    k_gemm_tile<64><<<gGemm, 256, 0, stream>>>(bufB, W3, dinv, bufA, N);
    k_aggregate16<<<gAgg, 256, 0, stream>>>(bufA, ssrc, offs, dinv, b3, bufB, N, 0);

    // mean-pool per graph + linear head
    k_pool_classify<<<B, 64, 0, stream>>>(bufB, segs, sege, Wl, bl, out, C);
}

// Round 6
// 192.947 us; speedup vs baseline: 2.1764x; 1.0849x over previous
//
#include <hip/hip_runtime.h>

#define NBSHIFT 8   // 256 nodes per dst-bucket
#define CHUNK 4096  // edges per binning block

// fp32 -> bf16 (round-to-nearest-even), and bf16-pair -> fp32 helpers
__device__ inline unsigned short f2bf(float f) {
    unsigned u = __builtin_bit_cast(unsigned, f);
    unsigned r = u + 0x7FFFu + ((u >> 16) & 1u);
    return (unsigned short)(r >> 16);
}

// ---------------- CSR construction (bucket pipeline) ----------------

// fused: blocks [0,nbChunk) histogram dst-buckets; blocks [nbChunk,..) do
// segment-boundary detection on the sorted batch array.
__global__ __launch_bounds__(256) void k_count_seg(const int* __restrict__ dst,
                                                   int* __restrict__ bcnt, int E, int NB,
                                                   const int* __restrict__ batch,
                                                   int* __restrict__ ss,
                                                   int* __restrict__ se, int N,
                                                   int nbChunk) {
    __shared__ int lcnt[256];
    int t = threadIdx.x;
    if (blockIdx.x < (unsigned)nbChunk) {
        int e0 = blockIdx.x * CHUNK;
        int e1 = min(e0 + CHUNK, E);
        lcnt[t] = 0;
        __syncthreads();
        for (int i = e0 + t; i < e1; i += 256)
            atomicAdd(&lcnt[dst[i] >> NBSHIFT], 1);
        __syncthreads();
        if (t < NB && lcnt[t]) atomicAdd(&bcnt[t], lcnt[t]);
    } else {
        int i = (blockIdx.x - nbChunk) * 256 + t;
        if (i == 0) ss[batch[0]] = 0;
        if (i == N - 1) se[batch[N - 1]] = N;
        if (i < N - 1) {
            int b0 = batch[i], b1 = batch[i + 1];
            if (b0 != b1) { se[b0] = i + 1; ss[b1] = i + 1; }
        }
    }
}

// partition edges into dst-buckets; pair packed to 4B: (dst&255)<<24 | src.
// bucket bases recomputed in-block from bcnt (196-wide scan); allocation via
// zeroed bcur0 cursors.
__global__ __launch_bounds__(256) void k_bin(const int* __restrict__ src,
                                             const int* __restrict__ dst,
                                             const int* __restrict__ bcnt,
                                             int* __restrict__ bcur0,
                                             unsigned* __restrict__ pairbuf,
                                             int E, int NB) {
    __shared__ int sd[256];
    __shared__ int lcnt[256];
    __shared__ int lbase[256];
    int t = threadIdx.x;
    int v = (t < NB) ? bcnt[t] : 0;
    sd[t] = v;
    lcnt[t] = 0;
    __syncthreads();
    int sum = v;
    for (int d = 1; d < 256; d <<= 1) {
        int add = (t >= d) ? sd[t - d] : 0;
        __syncthreads();
        sum += add;
        sd[t] = sum;
        __syncthreads();
    }
    int bbase_t = sum - v;            // exclusive scan = bucket base
    int e0 = blockIdx.x * CHUNK;
    int e1 = min(e0 + CHUNK, E);
    for (int i = e0 + t; i < e1; i += 256)
        atomicAdd(&lcnt[dst[i] >> NBSHIFT], 1);
    __syncthreads();
    if (t < NB) {
        int c = lcnt[t];
        lbase[t] = bbase_t + (c ? atomicAdd(&bcur0[t], c) : 0);
        lcnt[t] = 0;
    }
    __syncthreads();
    for (int i = e0 + t; i < e1; i += 256) {
        int d = dst[i];
        int b = d >> NBSHIFT;
        int pos = lbase[b] + atomicAdd(&lcnt[b], 1);
        pairbuf[pos] = ((unsigned)(d & 255) << 24) | (unsigned)src[i];
    }
}

// one block per bucket: recompute base via in-block scan of bcnt, then LDS
// histogram -> deg/dinv, LDS scan -> offs, LDS cursors -> ssrc.
__global__ __launch_bounds__(256) void k_build(const unsigned* __restrict__ pairbuf,
                                               const int* __restrict__ bcnt,
                                               int* __restrict__ offs,
                                               float* __restrict__ dinv,
                                               int* __restrict__ ssrc, int N, int NB,
                                               int E) {
    __shared__ int sd[256];
    __shared__ int sexcl[256];
    __shared__ int cnt[256];
    __shared__ int cur[256];
    int b = blockIdx.x;
    int t = threadIdx.x;
    int v = (t < NB) ? bcnt[t] : 0;
    sd[t] = v;
    cnt[t] = 0;
    __syncthreads();
    int sum = v;
    for (int d = 1; d < 256; d <<= 1) {
        int add = (t >= d) ? sd[t - d] : 0;
        __syncthreads();
        sum += add;
        sd[t] = sum;
        __syncthreads();
    }
    sexcl[t] = sum - v;
    __syncthreads();
    int s0 = sexcl[b];
    int s1 = s0 + ((b < NB) ? bcnt[b] : 0);
    for (int i = s0 + t; i < s1; i += 256)
        atomicAdd(&cnt[pairbuf[i] >> 24], 1);
    __syncthreads();
    int c = cnt[t];
    sd[t] = c;
    __syncthreads();
    int sum2 = c;
    for (int d = 1; d < 256; d <<= 1) {
        int add = (t >= d) ? sd[t - d] : 0;
        __syncthreads();
        sum2 += add;
        sd[t] = sum2;
        __syncthreads();
    }
    int excl2 = sum2 - c;
    int node = (b << NBSHIFT) + t;
    if (node < N) {
        offs[node] = s0 + excl2;
        dinv[node] = rsqrtf((float)c + 1.0f);   // deg + 1 self-loop
    }
    if (b == 0 && t == 0) offs[N] = E;
    cur[t] = s0 + excl2;
    __syncthreads();
    for (int i = s0 + t; i < s1; i += 256) {
        unsigned p = pairbuf[i];
        int pos = atomicAdd(&cur[p >> 24], 1);
        ssrc[pos] = (int)(p & 0x00FFFFFFu);
    }
}

// ---------------- per-layer compute ----------------

// hs[v][f] = (in[v] @ W)[f] * dinv[v] rounded to bf16;  in: [N,K] fp32, out: [N,64] bf16
template <int K>
__global__ __launch_bounds__(256) void k_gemm_tile(const float* __restrict__ in,
                                                   const float* __restrict__ W,
                                                   const float* __restrict__ dinv,
                                                   unsigned short* __restrict__ out,
                                                   int N) {
    __shared__ float sX[K][64];
    __shared__ float sW[K][64];
    int t = threadIdx.x;
    int w = t >> 6, l = t & 63;
    int node0 = blockIdx.x * 64;

    for (int i = t; i < K * 16; i += 256)
        ((float4*)&sW[0][0])[i] = ((const float4*)W)[i];

    {
        int node = node0 + l;
        bool ok = node < N;
        const float* rp = in + (size_t)node * K;
        for (int k0 = w * (K / 4); k0 < (w + 1) * (K / 4); k0 += 4) {
            float4 v = ok ? *(const float4*)(rp + k0) : make_float4(0.f, 0.f, 0.f, 0.f);
            sX[k0 + 0][l] = v.x;
            sX[k0 + 1][l] = v.y;
            sX[k0 + 2][l] = v.z;
            sX[k0 + 3][l] = v.w;
        }
    }
    __syncthreads();

    int fg  = l & 15;
    int ngl = w * 4 + (l >> 4);

    float4 a0 = {0.f, 0.f, 0.f, 0.f};
    float4 a1 = {0.f, 0.f, 0.f, 0.f};
    float4 a2 = {0.f, 0.f, 0.f, 0.f};
    float4 a3 = {0.f, 0.f, 0.f, 0.f};

#pragma unroll 8
    for (int k = 0; k < K; ++k) {
        float4 xv = *(const float4*)(&sX[k][ngl * 4]);
        float4 wv = *(const float4*)(&sW[k][fg * 4]);
        a0.x += xv.x * wv.x; a0.y += xv.x * wv.y; a0.z += xv.x * wv.z; a0.w += xv.x * wv.w;
        a1.x += xv.y * wv.x; a1.y += xv.y * wv.y; a1.z += xv.y * wv.z; a1.w += xv.y * wv.w;
        a2.x += xv.z * wv.x; a2.y += xv.z * wv.y; a2.z += xv.z * wv.z; a2.w += xv.z * wv.w;
        a3.x += xv.w * wv.x; a3.y += xv.w * wv.y; a3.z += xv.w * wv.z; a3.w += xv.w * wv.w;
    }

    int nbase = node0 + ngl * 4;
    float4 accs[4] = {a0, a1, a2, a3};
#pragma unroll
    for (int i = 0; i < 4; ++i) {
        int n = nbase + i;
        if (n < N) {
            float s = dinv[n];
            float4 o = accs[i];
            ushort4 ob;
            ob.x = f2bf(o.x * s);
            ob.y = f2bf(o.y * s);
            ob.z = f2bf(o.z * s);
            ob.w = f2bf(o.w * s);
            *(ushort4*)(out + (size_t)n * 64 + fg * 4) = ob;
        }
    }
}

// one wave per node; lane = g*16+fl; 16 bf16 rows in flight per iteration
// (each 16-lane subgroup issues 4 independent uint2 gathers = 8B/lane,
// one coalesced 128B line per row); fp32 accumulate; shfl_xor(16,32) merge.
__global__ __launch_bounds__(256) void k_aggregate16(const unsigned short* __restrict__ hs,
                                                     const int* __restrict__ ssrc,
                                                     const int* __restrict__ offs,
                                                     const float* __restrict__ dinv,
                                                     const float* __restrict__ bias,
                                                     float* __restrict__ out, int N,
                                                     int do_relu) {
    int t = threadIdx.x;
    int wave = t >> 6, lane = t & 63;
    int g = lane >> 4, fl = lane & 15;
    int v = blockIdx.x * 4 + wave;
    if (v >= N) return;
    int start = offs[v];
    int cnt = offs[v + 1] - start;

    float4 acc = {0.f, 0.f, 0.f, 0.f};
#define BF_ACC(p)                                                              \
    do {                                                                       \
        acc.x += __builtin_bit_cast(float, (p).x << 16);                       \
        acc.y += __builtin_bit_cast(float, (p).x & 0xFFFF0000u);               \
        acc.z += __builtin_bit_cast(float, (p).y << 16);                       \
        acc.w += __builtin_bit_cast(float, (p).y & 0xFFFF0000u);               \
    } while (0)

    if (g == 0) {  // self-loop term (pre-scaled by dinv[v])
        uint2 p = *(const uint2*)(hs + (size_t)v * 64 + fl * 4);
        BF_ACC(p);
    }

    int j = 0;
    int cnt16 = cnt & ~15;
    for (; j < cnt16; j += 16) {
        int s0 = ssrc[start + j + g];
        int s1 = ssrc[start + j + 4 + g];
        int s2 = ssrc[start + j + 8 + g];
        int s3 = ssrc[start + j + 12 + g];
        uint2 h0 = *(const uint2*)(hs + (size_t)s0 * 64 + fl * 4);
        uint2 h1 = *(const uint2*)(hs + (size_t)s1 * 64 + fl * 4);
        uint2 h2 = *(const uint2*)(hs + (size_t)s2 * 64 + fl * 4);
        uint2 h3 = *(const uint2*)(hs + (size_t)s3 * 64 + fl * 4);
        BF_ACC(h0); BF_ACC(h1); BF_ACC(h2); BF_ACC(h3);
    }
    int cnt4 = cnt & ~3;
    for (; j < cnt4; j += 4) {
        int s = ssrc[start + j + g];
        uint2 h = *(const uint2*)(hs + (size_t)s * 64 + fl * 4);
        BF_ACC(h);
    }
    int rem = cnt - cnt4;
    if (g < rem) {
        int s = ssrc[start + cnt4 + g];
        uint2 h = *(const uint2*)(hs + (size_t)s * 64 + fl * 4);
        BF_ACC(h);
    }
#undef BF_ACC

    acc.x += __shfl_xor(acc.x, 16); acc.y += __shfl_xor(acc.y, 16);
    acc.z += __shfl_xor(acc.z, 16); acc.w += __shfl_xor(acc.w, 16);
    acc.x += __shfl_xor(acc.x, 32); acc.y += __shfl_xor(acc.y, 32);
    acc.z += __shfl_xor(acc.z, 32); acc.w += __shfl_xor(acc.w, 32);

    if (g == 0) {
        float s = dinv[v];
        float4 bv = *(const float4*)(bias + fl * 4);
        float4 o;
        o.x = acc.x * s + bv.x;
        o.y = acc.y * s + bv.y;
        o.z = acc.z * s + bv.z;
        o.w = acc.w * s + bv.w;
        if (do_relu) {
            o.x = fmaxf(o.x, 0.f); o.y = fmaxf(o.y, 0.f);
            o.z = fmaxf(o.z, 0.f); o.w = fmaxf(o.w, 0.f);
        }
        *(float4*)(out + (size_t)v * 64 + fl * 4) = o;
    }
}

// one wave per graph: 4 nodes in flight (g-split), float4 per lane; then 64x10 head.
__global__ __launch_bounds__(64) void k_pool_classify(const float* __restrict__ h,
                                                      const int* __restrict__ ss,
                                                      const int* __restrict__ se,
                                                      const float* __restrict__ Wl,
                                                      const float* __restrict__ bl,
                                                      float* __restrict__ out, int C) {
    int b = blockIdx.x;
    int lane = threadIdx.x;
    int g = lane >> 4, fl = lane & 15;
    int s = ss[b], e = se[b];
    float4 acc = {0.f, 0.f, 0.f, 0.f};
#pragma unroll 2
    for (int v = s + g; v < e; v += 4) {
        float4 hv = *(const float4*)(h + (size_t)v * 64 + fl * 4);
        acc.x += hv.x; acc.y += hv.y; acc.z += hv.z; acc.w += hv.w;
    }
    acc.x += __shfl_xor(acc.x, 16); acc.y += __shfl_xor(acc.y, 16);
    acc.z += __shfl_xor(acc.z, 16); acc.w += __shfl_xor(acc.w, 16);
    acc.x += __shfl_xor(acc.x, 32); acc.y += __shfl_xor(acc.y, 32);
    acc.z += __shfl_xor(acc.z, 32); acc.w += __shfl_xor(acc.w, 32);

    if (g == 0) {
        int cnt = e - s;
        if (cnt < 1) cnt = 1;
        float inv = 1.0f / (float)cnt;
        float4 p;
        p.x = acc.x * inv; p.y = acc.y * inv; p.z = acc.z * inv; p.w = acc.w * inv;
        int f0 = fl * 4;
        for (int c = 0; c < C; ++c) {
            float tt = p.x * Wl[(f0 + 0) * C + c] + p.y * Wl[(f0 + 1) * C + c]
                     + p.z * Wl[(f0 + 2) * C + c] + p.w * Wl[(f0 + 3) * C + c];
            tt += __shfl_xor(tt, 1); tt += __shfl_xor(tt, 2);
            tt += __shfl_xor(tt, 4); tt += __shfl_xor(tt, 8);
            if (fl == 0) out[b * C + c] = tt + bl[c];
        }
    }
}

// ---------------- launch ----------------

extern "C" void kernel_launch(void* const* d_in, const int* in_sizes, int n_in,
                              void* d_out, int out_size, void* d_ws, size_t ws_size,
                              hipStream_t stream) {
    const float* x    = (const float*)d_in[0];
    const int*   ei   = (const int*)d_in[1];
    const int*   batch= (const int*)d_in[2];
    const float* W1   = (const float*)d_in[3];
    const float* b1   = (const float*)d_in[4];
    const float* W2   = (const float*)d_in[5];
    const float* b2   = (const float*)d_in[6];
    const float* W3   = (const float*)d_in[7];
    const float* b3   = (const float*)d_in[8];
    const float* Wl   = (const float*)d_in[9];
    const float* bl   = (const float*)d_in[10];
    float* out = (float*)d_out;

    const int N = in_sizes[2];          // 50000
    const int E = in_sizes[1] / 2;      // 800000
    const int C = 10;
    const int B = out_size / C;         // 512
    const int NB = (N + (1 << NBSHIFT) - 1) >> NBSHIFT;   // 196 buckets

    char* ws = (char*)d_ws;
    auto alloc = [&](size_t bytes) {
        char* p = ws;
        ws += (bytes + 255) & ~(size_t)255;
        return p;
    };
    // contiguous zero region: bcnt | bcur0 | segs | sege  (single memset)
    int*   zreg    = (int*)alloc((size_t)(2 * NB + 2 * B) * 4);
    int*   bcnt    = zreg;
    int*   bcur0   = zreg + NB;
    int*   segs    = zreg + 2 * NB;
    int*   sege    = zreg + 2 * NB + B;
    float* dinv    = (float*)alloc((size_t)N * 4);
    int*   offs    = (int*)alloc((size_t)(N + 1) * 4);
    int*   ssrc    = (int*)alloc((size_t)E * 4);
    unsigned short* hsb = (unsigned short*)alloc((size_t)N * 64 * 2);  // bf16 hs
    float* bufF    = (float*)alloc((size_t)N * 64 * 4);                // fp32 layer out
    // pairbuf (E * 4B = 3.2MB) aliases bufF (12.8MB): consumed by k_build before
    // the first aggregate writes bufF (same-stream ordering).
    unsigned* pairbuf = (unsigned*)bufF;

    const int* src = ei;
    const int* dst = ei + E;

    hipMemsetAsync(zreg, 0, (size_t)(2 * NB + 2 * B) * 4, stream);

    int nbChunk = (E + CHUNK - 1) / CHUNK;
    int nbN = (N + 255) / 256;

    k_count_seg<<<nbChunk + nbN, 256, 0, stream>>>(dst, bcnt, E, NB,
                                                   batch, segs, sege, N, nbChunk);
    k_bin<<<nbChunk, 256, 0, stream>>>(src, dst, bcnt, bcur0, pairbuf, E, NB);
    k_build<<<NB, 256, 0, stream>>>(pairbuf, bcnt, offs, dinv, ssrc, N, NB, E);

    int gGemm = (N + 63) / 64;
    int gAgg  = (N + 3) / 4;

    // layer 1: x[N,128] @ W1 -> bf16 hs -> relu(agg) fp32
    k_gemm_tile<128><<<gGemm, 256, 0, stream>>>(x, W1, dinv, hsb, N);
    k_aggregate16<<<gAgg, 256, 0, stream>>>(hsb, ssrc, offs, dinv, b1, bufF, N, 1);
    // layer 2
    k_gemm_tile<64><<<gGemm, 256, 0, stream>>>(bufF, W2, dinv, hsb, N);
    k_aggregate16<<<gAgg, 256, 0, stream>>>(hsb, ssrc, offs, dinv, b2, bufF, N, 1);
    // layer 3 (no relu)
    k_gemm_tile<64><<<gGemm, 256, 0, stream>>>(bufF, W3, dinv, hsb, N);
    k_aggregate16<<<gAgg, 256, 0, stream>>>(hsb, ssrc, offs, dinv, b3, bufF, N, 0);

    // mean-pool per graph + linear head
    k_pool_classify<<<B, 64, 0, stream>>>(bufF, segs, sege, Wl, bl, out, C);
}